// Round 11
// baseline (326.183 us; speedup 1.0000x reference)
//
#include <hip/hip_runtime.h>
#include <hip/hip_bf16.h>
#include <math.h>

constexpr int B_ = 8, L_ = 256, D_ = 256, H_ = 8, DK_ = 32, NL_ = 4, V_ = 2048, FF_ = 1024;
constexpr int N_ = B_ * L_;
constexpr float EPS_ = 1e-5f;
constexpr int LDW_ = 56;  // 112B rows: 16B-aligned, ds_read_b128 bank starts 28r%32 -> free 2-way

typedef short bf16x8 __attribute__((ext_vector_type(8)));
typedef float f32x4 __attribute__((ext_vector_type(4)));
typedef _Float16 f16x4 __attribute__((ext_vector_type(4)));

__device__ __forceinline__ short f2b(float f) {
    union { __hip_bfloat16 h; short s; } u;
    u.h = __float2bfloat16(f);
    return u.s;
}

__device__ __forceinline__ int4 pack8(const float* v) {
    union { short s[8]; int4 q; } u;
#pragma unroll
    for (int j = 0; j < 8; ++j) u.s[j] = f2b(v[j]);
    return u.q;
}

// All weight transposes (fp32 [K,N] -> bf16 [N,K]) + embed in ONE launch; flat blockIdx decode.
__global__ void transpose_all(const float* __restrict__ Wq, const float* __restrict__ Wk,
                              const float* __restrict__ Wv, const float* __restrict__ Wo,
                              const float* __restrict__ W1, const float* __restrict__ W2,
                              const float* __restrict__ Wgen,
                              short* __restrict__ wqT, short* __restrict__ wkT,
                              short* __restrict__ wvT, short* __restrict__ woT,
                              short* __restrict__ w1T, short* __restrict__ w2T,
                              short* __restrict__ wgT,
                              const int* __restrict__ tokens, const int* __restrict__ positions,
                              const float* __restrict__ vtab, const float* __restrict__ ctab,
                              const float* __restrict__ ptab, float* __restrict__ x) {
    __shared__ float tile[32][33];
    int id = blockIdx.x;
    if (id >= 3584) {  // embed: x[n,d] = vtab[tok]*16 + ctab[p%3] + ptab[p/3]
        int n = id - 3584;
        int d = threadIdx.y * 32 + threadIdx.x;
        int tok = tokens[n], p = positions[n];
        x[n * D_ + d] = vtab[tok * D_ + d] * 16.0f + ctab[(p % 3) * D_ + d] + ptab[(p / 3) * D_ + d];
        return;
    }
    const float* src;
    short* dst;
    int K, Nn, tx, ty;
    if (id < 1024) {
        int m = id >> 8, rem = id & 255, layer = rem >> 6, tt = rem & 63;
        K = 256; Nn = 256; tx = tt & 7; ty = tt >> 3;
        size_t off = (size_t)layer * 256 * 256;
        if (m == 0) { src = Wq + off; dst = wqT + off; }
        else if (m == 1) { src = Wk + off; dst = wkT + off; }
        else if (m == 2) { src = Wv + off; dst = wvT + off; }
        else { src = Wo + off; dst = woT + off; }
    } else if (id < 2048) {
        int rem = id - 1024, layer = rem >> 8, tt = rem & 255;
        K = 256; Nn = 1024; tx = tt & 31; ty = tt >> 5;
        size_t off = (size_t)layer * 256 * 1024;
        src = W1 + off; dst = w1T + off;
    } else if (id < 3072) {
        int rem = id - 2048, layer = rem >> 8, tt = rem & 255;
        K = 1024; Nn = 256; tx = tt & 7; ty = tt >> 3;
        size_t off = (size_t)layer * 1024 * 256;
        src = W2 + off; dst = w2T + off;
    } else {
        int tt = id - 3072;
        K = 256; Nn = 2048; tx = tt & 63; ty = tt >> 6;
        src = Wgen; dst = wgT;
    }
    int n0 = tx * 32, k0 = ty * 32;
    int x_ = threadIdx.x, y_ = threadIdx.y;  // 32 x 8
#pragma unroll
    for (int i = 0; i < 32; i += 8)
        tile[y_ + i][x_] = src[(size_t)(k0 + y_ + i) * Nn + n0 + x_];
    __syncthreads();
#pragma unroll
    for (int i = 0; i < 32; i += 8)
        dst[(size_t)(n0 + y_ + i) * K + k0 + x_] = f2b(tile[x_][y_ + i]);
}

// EPI: 1 = bias+relu -> bf16; 2 = atomicAdd fp32 (+bias from kz==0); 3 = bias -> fp32;
//      4 = store bf16; 5 = store f16
template <int EPI, bool HAS_BIAS>
__device__ __forceinline__ void gemm_epilogue(f32x4 acc00, f32x4 acc01, f32x4 acc10, f32x4 acc11,
                                              const float* __restrict__ bias, float* __restrict__ Cf,
                                              short* __restrict__ Cb, int Nout, int kz,
                                              int m0, int n0, int mo, int no, int quad, int r) {
#pragma unroll
    for (int i = 0; i < 2; ++i) {
#pragma unroll
        for (int j = 0; j < 2; ++j) {
            f32x4 acc = (i == 0) ? (j == 0 ? acc00 : acc01) : (j == 0 ? acc10 : acc11);
            int col = n0 + no + j * 16 + r;
            float bval = HAS_BIAS ? bias[col] : 0.f;
#pragma unroll
            for (int p = 0; p < 4; ++p) {
                int row = m0 + mo + i * 16 + quad * 4 + p;
                float v = acc[p];
                if (EPI == 1) {
                    Cb[(size_t)row * Nout + col] = f2b(fmaxf(v + bval, 0.f));
                } else if (EPI == 2) {
                    float add = v + ((HAS_BIAS && kz == 0) ? bval : 0.f);
                    atomicAdd(&Cf[(size_t)row * Nout + col], add);
                } else if (EPI == 3) {
                    Cf[(size_t)row * Nout + col] = v + bval;
                } else if (EPI == 4) {
                    Cb[(size_t)row * Nout + col] = f2b(v);
                } else {
                    ((_Float16*)Cb)[(size_t)row * Nout + col] = (_Float16)v;
                }
            }
        }
    }
}

// 64x64 tile bf16 MFMA GEMM, ping-pong double-buffered LDS: ONE barrier per K-step.
template <int EPI, bool HAS_BIAS>
__device__ __forceinline__ void gemm_body(const short* __restrict__ A, const short* __restrict__ Bt,
                                          const float* __restrict__ bias, float* __restrict__ Cf,
                                          short* __restrict__ Cb, int M, int K, int Nout,
                                          int kbeg, int kend, int kz) {
    __shared__ short As[2][64][LDW_];
    __shared__ short Bs[2][64][LDW_];
    int t = threadIdx.x;
    int m0 = blockIdx.x * 64, n0 = blockIdx.y * 64;
    int sr = t >> 2, sc = (t & 3) * 8;
    int lane = t & 63, w = t >> 6;
    int mo = (w & 1) * 32, no = (w >> 1) * 32;
    int quad = lane >> 4, r = lane & 15;
    f32x4 acc00 = {}, acc01 = {}, acc10 = {}, acc11 = {};
    const short* Ap = &A[(size_t)(m0 + sr) * K + sc];
    const short* Bp = &Bt[(size_t)(n0 + sr) * K + sc];
    int4 av = *(const int4*)(Ap + kbeg);
    int4 bv = *(const int4*)(Bp + kbeg);
    *(int4*)&As[0][sr][sc] = av;
    *(int4*)&Bs[0][sr][sc] = bv;
    if (kbeg + 32 < kend) {
        av = *(const int4*)(Ap + kbeg + 32);
        bv = *(const int4*)(Bp + kbeg + 32);
    }
    __syncthreads();
    int p = 0;
    for (int k0 = kbeg; k0 < kend; k0 += 32, p ^= 1) {
        if (k0 + 32 < kend) {
            *(int4*)&As[p ^ 1][sr][sc] = av;
            *(int4*)&Bs[p ^ 1][sr][sc] = bv;
            if (k0 + 64 < kend) {
                av = *(const int4*)(Ap + k0 + 64);
                bv = *(const int4*)(Bp + k0 + 64);
            }
        }
        bf16x8 a0 = *(const bf16x8*)&As[p][mo + r][quad * 8];
        bf16x8 a1 = *(const bf16x8*)&As[p][mo + 16 + r][quad * 8];
        bf16x8 b0 = *(const bf16x8*)&Bs[p][no + r][quad * 8];
        bf16x8 b1 = *(const bf16x8*)&Bs[p][no + 16 + r][quad * 8];
        acc00 = __builtin_amdgcn_mfma_f32_16x16x32_bf16(a0, b0, acc00, 0, 0, 0);
        acc01 = __builtin_amdgcn_mfma_f32_16x16x32_bf16(a0, b1, acc01, 0, 0, 0);
        acc10 = __builtin_amdgcn_mfma_f32_16x16x32_bf16(a1, b0, acc10, 0, 0, 0);
        acc11 = __builtin_amdgcn_mfma_f32_16x16x32_bf16(a1, b1, acc11, 0, 0, 0);
        if (k0 + 32 < kend) __syncthreads();
    }
    gemm_epilogue<EPI, HAS_BIAS>(acc00, acc01, acc10, acc11, bias, Cf, Cb, Nout, kz,
                                 m0, n0, mo, no, quad, r);
}

// LN fused into GEMM: A = LN(x) computed in-block (K fixed at 256), same ping-pong loop.
template <int EPI, bool HAS_BIAS>
__device__ __forceinline__ void gemm_ln_body(const float* __restrict__ X,
                                             const float* __restrict__ lg, const float* __restrict__ lb,
                                             const short* __restrict__ Bt,
                                             const float* __restrict__ bias, float* __restrict__ Cf,
                                             short* __restrict__ Cb, int Nout) {
    __shared__ short As[2][64][LDW_];
    __shared__ short Bs[2][64][LDW_];
    __shared__ float gs[256], bs_[256];
    int t = threadIdx.x;
    int m0 = blockIdx.x * 64, n0 = blockIdx.y * 64;
    int sr = t >> 2, sc = (t & 3) * 8;
    int lane = t & 63, w = t >> 6;
    int mo = (w & 1) * 32, no = (w >> 1) * 32;
    int quad = lane >> 4, r = lane & 15;

    float xv[64];
    const float* xp = &X[(size_t)(m0 + sr) * 256 + sc];
#pragma unroll
    for (int c = 0; c < 8; ++c) {
        *(float4*)&xv[c * 8] = *(const float4*)(xp + c * 32);
        *(float4*)&xv[c * 8 + 4] = *(const float4*)(xp + c * 32 + 4);
    }
    const short* Bp = &Bt[(size_t)(n0 + sr) * 256 + sc];
    int4 bv = *(const int4*)Bp;
    gs[t] = lg[t];
    bs_[t] = lb[t];

    float s1 = 0.f, s2 = 0.f;
#pragma unroll
    for (int j = 0; j < 64; ++j) {
        s1 += xv[j];
        s2 += xv[j] * xv[j];
    }
    s1 += __shfl_xor(s1, 1, 64); s1 += __shfl_xor(s1, 2, 64);
    s2 += __shfl_xor(s2, 1, 64); s2 += __shfl_xor(s2, 2, 64);
    float mean = s1 * (1.0f / 256.0f);
    float inv = rsqrtf(s2 * (1.0f / 256.0f) - mean * mean + EPS_);
    __syncthreads();  // gs/bs_ visible

    int4 a_regs[8];
#pragma unroll
    for (int c = 0; c < 8; ++c) {
        float tmp[8];
#pragma unroll
        for (int j = 0; j < 8; ++j)
            tmp[j] = (xv[c * 8 + j] - mean) * inv * gs[c * 32 + sc + j] + bs_[c * 32 + sc + j];
        a_regs[c] = pack8(tmp);
    }

    *(int4*)&As[0][sr][sc] = a_regs[0];
    *(int4*)&Bs[0][sr][sc] = bv;
    bv = *(const int4*)(Bp + 32);
    __syncthreads();

    f32x4 acc00 = {}, acc01 = {}, acc10 = {}, acc11 = {};
#pragma unroll
    for (int c = 0; c < 8; ++c) {
        int p = c & 1;
        if (c + 1 < 8) {
            *(int4*)&As[p ^ 1][sr][sc] = a_regs[c + 1];
            *(int4*)&Bs[p ^ 1][sr][sc] = bv;
            if (c + 2 < 8) bv = *(const int4*)(Bp + (c + 2) * 32);
        }
        bf16x8 a0 = *(const bf16x8*)&As[p][mo + r][quad * 8];
        bf16x8 a1 = *(const bf16x8*)&As[p][mo + 16 + r][quad * 8];
        bf16x8 b0 = *(const bf16x8*)&Bs[p][no + r][quad * 8];
        bf16x8 b1 = *(const bf16x8*)&Bs[p][no + 16 + r][quad * 8];
        acc00 = __builtin_amdgcn_mfma_f32_16x16x32_bf16(a0, b0, acc00, 0, 0, 0);
        acc01 = __builtin_amdgcn_mfma_f32_16x16x32_bf16(a0, b1, acc01, 0, 0, 0);
        acc10 = __builtin_amdgcn_mfma_f32_16x16x32_bf16(a1, b0, acc10, 0, 0, 0);
        acc11 = __builtin_amdgcn_mfma_f32_16x16x32_bf16(a1, b1, acc11, 0, 0, 0);
        if (c + 1 < 8) __syncthreads();
    }
    gemm_epilogue<EPI, HAS_BIAS>(acc00, acc01, acc10, acc11, bias, Cf, Cb, Nout, 0,
                                 m0, n0, mo, no, quad, r);
}

// fused LN2 + FFN1 (bias+relu -> bf16)
__global__ __launch_bounds__(256) void gemm_ln_relu(const float* __restrict__ X,
                                                    const float* __restrict__ lg, const float* __restrict__ lb,
                                                    const short* __restrict__ Bt, const float* __restrict__ bias,
                                                    short* __restrict__ C) {
    gemm_ln_body<1, true>(X, lg, lb, Bt, bias, nullptr, C, FF_);
}

// fused final LN + generator (bias -> fp32)
__global__ __launch_bounds__(256) void gemm_ln_bias(const float* __restrict__ X,
                                                    const float* __restrict__ lg, const float* __restrict__ lb,
                                                    const short* __restrict__ Bt, const float* __restrict__ bias,
                                                    float* __restrict__ C) {
    gemm_ln_body<3, true>(X, lg, lb, Bt, bias, C, nullptr, V_);
}

template <int SPLITK, bool HAS_BIAS>
__global__ __launch_bounds__(256) void gemm_accum(const short* __restrict__ A, const short* __restrict__ Bt,
                                                  const float* __restrict__ bias, float* __restrict__ C,
                                                  int M, int K, int Nout) {
    int Kp = K / SPLITK;
    int kz = blockIdx.z;
    gemm_body<2, HAS_BIAS>(A, Bt, bias, C, nullptr, M, K, Nout, kz * Kp, kz * Kp + Kp, kz);
}

// ====== fused LN1 + QKV + flash attention, one block per (batch, head) ======
// Phase A: per-(b,h) weight slices (16KB each, read ONCE — no redundancy) staged in LDS;
//          4 chunks of 64 rows: LN1(x) -> Af, mini-GEMMs (64x32, K=256) -> q/k/v in LDS.
// Phase B: 8 waves x 2 causal q-tiles {w, 15-w} = 17 k-tile units each (balanced),
//          K/V read from LDS; z written to global (Wo needs all heads).
// Eliminates 3MB/layer q/k/v global round-trip + one dispatch boundary per layer.
// All LDS row strides are 16B-aligned (528B / 80B) for legal ds_read_b128;
// bank starts: Af/Ws 4r%32 (2-way, free), q/k 20r%32 (2-way, free).
__global__ __launch_bounds__(512) void qkv_attn_kernel(const float* __restrict__ X,
                                                       const float* __restrict__ lg,
                                                       const float* __restrict__ lb,
                                                       const short* __restrict__ wqT,
                                                       const short* __restrict__ wkT,
                                                       const short* __restrict__ wvT,
                                                       short* __restrict__ z) {
    __shared__ short Af[64][264];                      // 33.8 KB
    __shared__ short Wsq[32][264], Wsk[32][264], Wsv[32][264];  // 50.7 KB
    __shared__ short qls[256][40], kls[256][40];       // 41 KB
    __shared__ _Float16 vls[256][40];                  // 20.5 KB
    __shared__ float gsh[256], bsh[256];               // 2 KB   (total ~148 KB, 1 block/CU)

    int t = threadIdx.x;  // 0..511
    int bh = blockIdx.x;
    int b = bh >> 3, h = bh & 7;
    int row0 = b * L_;
    int w = t >> 6, lane = t & 63;
    int quad = lane >> 4, r = lane & 15;

    if (t < 256) { gsh[t] = lg[t]; bsh[t] = lb[t]; }
    {   // stage weight slices: rows h*32..+31 of [256][256] (contiguous 16KB each)
        int wr = t >> 4, wc = (t & 15) * 16;
        const short* qs = &wqT[(size_t)(h * 32 + wr) * 256 + wc];
        const short* ks = &wkT[(size_t)(h * 32 + wr) * 256 + wc];
        const short* vs = &wvT[(size_t)(h * 32 + wr) * 256 + wc];
        *(int4*)&Wsq[wr][wc] = *(const int4*)qs;
        *(int4*)&Wsq[wr][wc + 8] = *(const int4*)(qs + 8);
        *(int4*)&Wsk[wr][wc] = *(const int4*)ks;
        *(int4*)&Wsk[wr][wc + 8] = *(const int4*)(ks + 8);
        *(int4*)&Wsv[wr][wc] = *(const int4*)vs;
        *(int4*)&Wsv[wr][wc + 8] = *(const int4*)(vs + 8);
    }

    // ---- Phase A: 4 chunks of 64 rows ----
    int xrow = t >> 3, xcl = (t & 7) * 32;  // thread owns 32 cols of one row
    int wm = (w & 3) * 16, wn = (w >> 2) * 16;
    for (int c = 0; c < 4; ++c) {
        float xv[32];
        const float* xp = &X[(size_t)(row0 + c * 64 + xrow) * 256 + xcl];
#pragma unroll
        for (int i = 0; i < 8; ++i)
            *(float4*)&xv[i * 4] = *(const float4*)(xp + i * 4);
        float s1 = 0.f, s2 = 0.f;
#pragma unroll
        for (int j = 0; j < 32; ++j) {
            s1 += xv[j];
            s2 += xv[j] * xv[j];
        }
        s1 += __shfl_xor(s1, 1, 64); s1 += __shfl_xor(s1, 2, 64); s1 += __shfl_xor(s1, 4, 64);
        s2 += __shfl_xor(s2, 1, 64); s2 += __shfl_xor(s2, 2, 64); s2 += __shfl_xor(s2, 4, 64);
        float mean = s1 * (1.0f / 256.0f);
        float inv = rsqrtf(s2 * (1.0f / 256.0f) - mean * mean + EPS_);
        __syncthreads();  // WAR on Af (prev chunk GEMM done); 1st iter: staging visible
#pragma unroll
        for (int i = 0; i < 4; ++i) {
            float tmp[8];
#pragma unroll
            for (int j = 0; j < 8; ++j)
                tmp[j] = (xv[i * 8 + j] - mean) * inv * gsh[xcl + i * 8 + j] + bsh[xcl + i * 8 + j];
            *(int4*)&Af[xrow][xcl + i * 8] = pack8(tmp);
        }
        __syncthreads();  // Af ready
        // wave w: rows band wm, col half wn; 3 matrices in one K-loop
        f32x4 aq = {}, ak = {}, av = {};
#pragma unroll
        for (int ks = 0; ks < 8; ++ks) {
            bf16x8 a = *(const bf16x8*)&Af[wm + r][ks * 32 + quad * 8];
            bf16x8 bq = *(const bf16x8*)&Wsq[wn + r][ks * 32 + quad * 8];
            bf16x8 bk = *(const bf16x8*)&Wsk[wn + r][ks * 32 + quad * 8];
            bf16x8 bv = *(const bf16x8*)&Wsv[wn + r][ks * 32 + quad * 8];
            aq = __builtin_amdgcn_mfma_f32_16x16x32_bf16(a, bq, aq, 0, 0, 0);
            ak = __builtin_amdgcn_mfma_f32_16x16x32_bf16(a, bk, ak, 0, 0, 0);
            av = __builtin_amdgcn_mfma_f32_16x16x32_bf16(a, bv, av, 0, 0, 0);
        }
#pragma unroll
        for (int p = 0; p < 4; ++p) {
            int orow = c * 64 + wm + quad * 4 + p;
            int ocol = wn + r;
            qls[orow][ocol] = f2b(aq[p]);
            kls[orow][ocol] = f2b(ak[p]);
            vls[orow][ocol] = (_Float16)av[p];
        }
    }
    __syncthreads();  // all q/k/v ready

    // ---- Phase B: flash attention, 2 q-tiles per wave ----
#pragma unroll
    for (int tk = 0; tk < 2; ++tk) {
        int qt = (tk == 0) ? w : 15 - w;
        bf16x8 qf = *(const bf16x8*)&qls[qt * 16 + r][quad * 8];
        f32x4 O0 = {}, O1 = {};
        float mA = -1e30f, den = 0.f;
        for (int kt = 0; kt <= qt; ++kt) {
            bf16x8 kf = *(const bf16x8*)&kls[kt * 16 + r][quad * 8];
            f16x4 va, vb;
#pragma unroll
            for (int i = 0; i < 4; ++i) {
                va[i] = vls[kt * 16 + quad * 4 + i][r];
                vb[i] = vls[kt * 16 + quad * 4 + i][16 + r];
            }
            f32x4 zero = {};
            f32x4 s = __builtin_amdgcn_mfma_f32_16x16x32_bf16(kf, qf, zero, 0, 0, 0);
#pragma unroll
            for (int i2 = 0; i2 < 4; ++i2) s[i2] *= 0.17677669529663687f;
            if (kt == qt) {
#pragma unroll
                for (int i2 = 0; i2 < 4; ++i2)
                    if (quad * 4 + i2 > r) s[i2] = -1e30f;
            }
            float tmax = fmaxf(fmaxf(s[0], s[1]), fmaxf(s[2], s[3]));
            tmax = fmaxf(tmax, __shfl_xor(tmax, 16, 64));
            tmax = fmaxf(tmax, __shfl_xor(tmax, 32, 64));
            float mn = fmaxf(mA, tmax);
            float alpha = __expf(mA - mn);
            mA = mn;
            float p0 = __expf(s[0] - mn), p1 = __expf(s[1] - mn);
            float p2 = __expf(s[2] - mn), p3 = __expf(s[3] - mn);
            float ts = (p0 + p1) + (p2 + p3);
            ts += __shfl_xor(ts, 16, 64);
            ts += __shfl_xor(ts, 32, 64);
            den = den * alpha + ts;
            f16x4 pf;
            pf[0] = (_Float16)p0; pf[1] = (_Float16)p1; pf[2] = (_Float16)p2; pf[3] = (_Float16)p3;
            float al[4];
#pragma unroll
            for (int i2 = 0; i2 < 4; ++i2) al[i2] = __shfl(alpha, quad * 4 + i2, 64);
#pragma unroll
            for (int i2 = 0; i2 < 4; ++i2) { O0[i2] *= al[i2]; O1[i2] *= al[i2]; }
            O0 = __builtin_amdgcn_mfma_f32_16x16x16f16(pf, va, O0, 0, 0, 0);
            O1 = __builtin_amdgcn_mfma_f32_16x16x16f16(pf, vb, O1, 0, 0, 0);
        }
#pragma unroll
        for (int i2 = 0; i2 < 4; ++i2) {
            float inv = 1.0f / __shfl(den, quad * 4 + i2, 64);
            int rowz = row0 + qt * 16 + quad * 4 + i2;
            z[(size_t)rowz * D_ + h * DK_ + r] = f2b(O0[i2] * inv);
            z[(size_t)rowz * D_ + h * DK_ + 16 + r] = f2b(O1[i2] * inv);
        }
    }
}

// in-place log_softmax over V=2048, one block per row
__global__ void lsm_kernel(float* __restrict__ logits) {
    __shared__ float rm[4], rs[4];
    int row = blockIdx.x, t = threadIdx.x;
    float* p = logits + (size_t)row * V_;
    float vals[8];
    float mx = -INFINITY;
#pragma unroll
    for (int i = 0; i < 8; ++i) {
        vals[i] = p[t + i * 256];
        mx = fmaxf(mx, vals[i]);
    }
#pragma unroll
    for (int off = 32; off; off >>= 1) mx = fmaxf(mx, __shfl_xor(mx, off, 64));
    int w = t >> 6;
    if ((t & 63) == 0) rm[w] = mx;
    __syncthreads();
    mx = fmaxf(fmaxf(rm[0], rm[1]), fmaxf(rm[2], rm[3]));
    float s = 0.f;
#pragma unroll
    for (int i = 0; i < 8; ++i) s += __expf(vals[i] - mx);
#pragma unroll
    for (int off = 32; off; off >>= 1) s += __shfl_xor(s, off, 64);
    if ((t & 63) == 0) rs[w] = s;
    __syncthreads();
    s = rs[0] + rs[1] + rs[2] + rs[3];
    float lse = mx + logf(s);
#pragma unroll
    for (int i = 0; i < 8; ++i) p[t + i * 256] = vals[i] - lse;
}

extern "C" void kernel_launch(void* const* d_in, const int* in_sizes, int n_in,
                              void* d_out, int out_size, void* d_ws, size_t ws_size,
                              hipStream_t stream) {
    const int* tokens = (const int*)d_in[0];
    const int* positions = (const int*)d_in[1];
    // d_in[2]=src, d_in[3]=dst: deterministic causal structure — unused
    const float* vtab = (const float*)d_in[4];
    const float* ctab = (const float*)d_in[5];
    const float* ptab = (const float*)d_in[6];
    const float* ln1_g = (const float*)d_in[7];
    const float* ln1_b = (const float*)d_in[8];
    const float* Wq = (const float*)d_in[9];
    const float* Wk = (const float*)d_in[10];
    const float* Wv = (const float*)d_in[11];
    const float* Wo = (const float*)d_in[12];
    const float* ln2_g = (const float*)d_in[13];
    const float* ln2_b = (const float*)d_in[14];
    const float* W1 = (const float*)d_in[15];
    const float* b1 = (const float*)d_in[16];
    const float* W2 = (const float*)d_in[17];
    const float* b2 = (const float*)d_in[18];
    const float* lnf_g = (const float*)d_in[19];
    const float* lnf_b = (const float*)d_in[20];
    const float* Wgen = (const float*)d_in[21];
    const float* bgen = (const float*)d_in[22];

    char* p = (char*)d_ws;
    float* x = (float*)p;      p += (size_t)N_ * D_ * 4;
    short* zbb = (short*)p;    p += (size_t)N_ * D_ * 2;
    short* hbb = (short*)p;    p += (size_t)N_ * FF_ * 2;
    short* wqT = (short*)p;    p += (size_t)NL_ * D_ * D_ * 2;
    short* wkT = (short*)p;    p += (size_t)NL_ * D_ * D_ * 2;
    short* wvT = (short*)p;    p += (size_t)NL_ * D_ * D_ * 2;
    short* woT = (short*)p;    p += (size_t)NL_ * D_ * D_ * 2;
    short* w1T = (short*)p;    p += (size_t)NL_ * D_ * FF_ * 2;
    short* w2T = (short*)p;    p += (size_t)NL_ * FF_ * D_ * 2;
    short* wgT = (short*)p;    p += (size_t)D_ * V_ * 2;
    float* out = (float*)d_out;

    dim3 tb(32, 8);
    transpose_all<<<5632, tb, 0, stream>>>(Wq, Wk, Wv, Wo, W1, W2, Wgen,
                                           wqT, wkT, wvT, woT, w1T, w2T, wgT,
                                           tokens, positions, vtab, ctab, ptab, x);

    dim3 gWo(N_ / 64, D_ / 64, 2);
    dim3 gW1(N_ / 64, FF_ / 64);
    dim3 gW2(N_ / 64, D_ / 64, 4);
    dim3 gGen(N_ / 64, V_ / 64);
    for (int i = 0; i < NL_; ++i) {
        qkv_attn_kernel<<<B_ * H_, 512, 0, stream>>>(x, ln1_g + i * D_, ln1_b + i * D_,
                                                     wqT + (size_t)i * D_ * D_,
                                                     wkT + (size_t)i * D_ * D_,
                                                     wvT + (size_t)i * D_ * D_, zbb);
        gemm_accum<2, false><<<gWo, 256, 0, stream>>>(zbb, woT + (size_t)i * D_ * D_, nullptr, x, N_, D_, D_);
        gemm_ln_relu<<<gW1, 256, 0, stream>>>(x, ln2_g + i * D_, ln2_b + i * D_,
                                              w1T + (size_t)i * D_ * FF_, b1 + (size_t)i * FF_, hbb);
        gemm_accum<4, true><<<gW2, 256, 0, stream>>>(hbb, w2T + (size_t)i * FF_ * D_, b2 + (size_t)i * D_,
                                                     x, N_, FF_, D_);
    }
    gemm_ln_bias<<<gGen, 256, 0, stream>>>(x, lnf_g, lnf_b, wgT, bgen, out);
    lsm_kernel<<<N_, 256, 0, stream>>>(out);
}

// Round 12
// 305.274 us; speedup vs baseline: 1.0685x; 1.0685x over previous
//
#include <hip/hip_runtime.h>
#include <hip/hip_bf16.h>
#include <math.h>

constexpr int B_ = 8, L_ = 256, D_ = 256, H_ = 8, DK_ = 32, NL_ = 4, V_ = 2048, FF_ = 1024;
constexpr int N_ = B_ * L_;
constexpr float EPS_ = 1e-5f;
constexpr int LDW_ = 56;  // 112B rows: 16B-aligned, ds_read_b128 bank starts 28r%32 -> free 2-way

typedef short bf16x8 __attribute__((ext_vector_type(8)));
typedef float f32x4 __attribute__((ext_vector_type(4)));
typedef _Float16 f16x4 __attribute__((ext_vector_type(4)));

__device__ __forceinline__ short f2b(float f) {
    union { __hip_bfloat16 h; short s; } u;
    u.h = __float2bfloat16(f);
    return u.s;
}

// All weight transposes (fp32 [K,N] -> bf16 [N,K]) + embed in ONE launch; flat blockIdx decode.
// id ranges: [0,1024) Wq/Wk/Wv/Wo; [1024,2048) W1; [2048,3072) W2; [3072,3584) Wgen;
//            [3584,5632) embed rows
__global__ void transpose_all(const float* __restrict__ Wq, const float* __restrict__ Wk,
                              const float* __restrict__ Wv, const float* __restrict__ Wo,
                              const float* __restrict__ W1, const float* __restrict__ W2,
                              const float* __restrict__ Wgen,
                              short* __restrict__ wqT, short* __restrict__ wkT,
                              short* __restrict__ wvT, short* __restrict__ woT,
                              short* __restrict__ w1T, short* __restrict__ w2T,
                              short* __restrict__ wgT,
                              const int* __restrict__ tokens, const int* __restrict__ positions,
                              const float* __restrict__ vtab, const float* __restrict__ ctab,
                              const float* __restrict__ ptab, float* __restrict__ x) {
    __shared__ float tile[32][33];
    int id = blockIdx.x;
    if (id >= 3584) {  // embed: x[n,d] = vtab[tok]*16 + ctab[p%3] + ptab[p/3]
        int n = id - 3584;
        int d = threadIdx.y * 32 + threadIdx.x;
        int tok = tokens[n], p = positions[n];
        x[n * D_ + d] = vtab[tok * D_ + d] * 16.0f + ctab[(p % 3) * D_ + d] + ptab[(p / 3) * D_ + d];
        return;
    }
    const float* src;
    short* dst;
    int K, Nn, tx, ty;
    if (id < 1024) {
        int m = id >> 8, rem = id & 255, layer = rem >> 6, tt = rem & 63;
        K = 256; Nn = 256; tx = tt & 7; ty = tt >> 3;
        size_t off = (size_t)layer * 256 * 256;
        if (m == 0) { src = Wq + off; dst = wqT + off; }
        else if (m == 1) { src = Wk + off; dst = wkT + off; }
        else if (m == 2) { src = Wv + off; dst = wvT + off; }
        else { src = Wo + off; dst = woT + off; }
    } else if (id < 2048) {
        int rem = id - 1024, layer = rem >> 8, tt = rem & 255;
        K = 256; Nn = 1024; tx = tt & 31; ty = tt >> 5;
        size_t off = (size_t)layer * 256 * 1024;
        src = W1 + off; dst = w1T + off;
    } else if (id < 3072) {
        int rem = id - 2048, layer = rem >> 8, tt = rem & 255;
        K = 1024; Nn = 256; tx = tt & 7; ty = tt >> 3;
        size_t off = (size_t)layer * 1024 * 256;
        src = W2 + off; dst = w2T + off;
    } else {
        int tt = id - 3072;
        K = 256; Nn = 2048; tx = tt & 63; ty = tt >> 6;
        src = Wgen; dst = wgT;
    }
    int n0 = tx * 32, k0 = ty * 32;
    int x_ = threadIdx.x, y_ = threadIdx.y;  // 32 x 8
#pragma unroll
    for (int i = 0; i < 32; i += 8)
        tile[y_ + i][x_] = src[(size_t)(k0 + y_ + i) * Nn + n0 + x_];
    __syncthreads();
#pragma unroll
    for (int i = 0; i < 32; i += 8)
        dst[(size_t)(n0 + y_ + i) * K + k0 + x_] = f2b(tile[x_][y_ + i]);
}

__device__ __forceinline__ int4 pack8(const float* v) {
    union { short s[8]; int4 q; } u;
#pragma unroll
    for (int j = 0; j < 8; ++j) u.s[j] = f2b(v[j]);
    return u.q;
}

// EPI: 1 = bias+relu -> bf16; 2 = atomicAdd fp32 (+bias from kz==0); 3 = bias -> fp32;
//      4 = store bf16; 5 = store f16
template <int EPI, bool HAS_BIAS>
__device__ __forceinline__ void gemm_epilogue(f32x4 acc00, f32x4 acc01, f32x4 acc10, f32x4 acc11,
                                              const float* __restrict__ bias, float* __restrict__ Cf,
                                              short* __restrict__ Cb, int Nout, int kz,
                                              int m0, int n0, int mo, int no, int quad, int r) {
#pragma unroll
    for (int i = 0; i < 2; ++i) {
#pragma unroll
        for (int j = 0; j < 2; ++j) {
            f32x4 acc = (i == 0) ? (j == 0 ? acc00 : acc01) : (j == 0 ? acc10 : acc11);
            int col = n0 + no + j * 16 + r;
            float bval = HAS_BIAS ? bias[col] : 0.f;
#pragma unroll
            for (int p = 0; p < 4; ++p) {
                int row = m0 + mo + i * 16 + quad * 4 + p;
                float v = acc[p];
                if (EPI == 1) {
                    Cb[(size_t)row * Nout + col] = f2b(fmaxf(v + bval, 0.f));
                } else if (EPI == 2) {
                    float add = v + ((HAS_BIAS && kz == 0) ? bval : 0.f);
                    atomicAdd(&Cf[(size_t)row * Nout + col], add);
                } else if (EPI == 3) {
                    Cf[(size_t)row * Nout + col] = v + bval;
                } else if (EPI == 4) {
                    Cb[(size_t)row * Nout + col] = f2b(v);
                } else {
                    ((_Float16*)Cb)[(size_t)row * Nout + col] = (_Float16)v;
                }
            }
        }
    }
}

// 64x64 tile bf16 MFMA GEMM, ping-pong double-buffered LDS: ONE barrier per K-step.
template <int EPI, bool HAS_BIAS>
__device__ __forceinline__ void gemm_body(const short* __restrict__ A, const short* __restrict__ Bt,
                                          const float* __restrict__ bias, float* __restrict__ Cf,
                                          short* __restrict__ Cb, int M, int K, int Nout,
                                          int kbeg, int kend, int kz) {
    __shared__ short As[2][64][LDW_];
    __shared__ short Bs[2][64][LDW_];
    int t = threadIdx.x;
    int m0 = blockIdx.x * 64, n0 = blockIdx.y * 64;
    int sr = t >> 2, sc = (t & 3) * 8;
    int lane = t & 63, w = t >> 6;
    int mo = (w & 1) * 32, no = (w >> 1) * 32;
    int quad = lane >> 4, r = lane & 15;
    f32x4 acc00 = {}, acc01 = {}, acc10 = {}, acc11 = {};
    const short* Ap = &A[(size_t)(m0 + sr) * K + sc];
    const short* Bp = &Bt[(size_t)(n0 + sr) * K + sc];
    int4 av = *(const int4*)(Ap + kbeg);
    int4 bv = *(const int4*)(Bp + kbeg);
    *(int4*)&As[0][sr][sc] = av;
    *(int4*)&Bs[0][sr][sc] = bv;
    if (kbeg + 32 < kend) {
        av = *(const int4*)(Ap + kbeg + 32);
        bv = *(const int4*)(Bp + kbeg + 32);
    }
    __syncthreads();
    int p = 0;
    for (int k0 = kbeg; k0 < kend; k0 += 32, p ^= 1) {
        if (k0 + 32 < kend) {
            *(int4*)&As[p ^ 1][sr][sc] = av;
            *(int4*)&Bs[p ^ 1][sr][sc] = bv;
            if (k0 + 64 < kend) {
                av = *(const int4*)(Ap + k0 + 64);
                bv = *(const int4*)(Bp + k0 + 64);
            }
        }
        bf16x8 a0 = *(const bf16x8*)&As[p][mo + r][quad * 8];
        bf16x8 a1 = *(const bf16x8*)&As[p][mo + 16 + r][quad * 8];
        bf16x8 b0 = *(const bf16x8*)&Bs[p][no + r][quad * 8];
        bf16x8 b1 = *(const bf16x8*)&Bs[p][no + 16 + r][quad * 8];
        acc00 = __builtin_amdgcn_mfma_f32_16x16x32_bf16(a0, b0, acc00, 0, 0, 0);
        acc01 = __builtin_amdgcn_mfma_f32_16x16x32_bf16(a0, b1, acc01, 0, 0, 0);
        acc10 = __builtin_amdgcn_mfma_f32_16x16x32_bf16(a1, b0, acc10, 0, 0, 0);
        acc11 = __builtin_amdgcn_mfma_f32_16x16x32_bf16(a1, b1, acc11, 0, 0, 0);
        if (k0 + 32 < kend) __syncthreads();
    }
    gemm_epilogue<EPI, HAS_BIAS>(acc00, acc01, acc10, acc11, bias, Cf, Cb, Nout, kz,
                                 m0, n0, mo, no, quad, r);
}

// LN fused into GEMM: A = LN(x) computed in-block (K fixed at 256), same ping-pong loop.
template <int EPI, bool HAS_BIAS>
__device__ __forceinline__ void gemm_ln_body(const float* __restrict__ X,
                                             const float* __restrict__ lg, const float* __restrict__ lb,
                                             const short* __restrict__ Bt,
                                             const float* __restrict__ bias, float* __restrict__ Cf,
                                             short* __restrict__ Cb, int Nout) {
    __shared__ short As[2][64][LDW_];
    __shared__ short Bs[2][64][LDW_];
    __shared__ float gs[256], bs_[256];
    int t = threadIdx.x;
    int m0 = blockIdx.x * 64, n0 = blockIdx.y * 64;
    int sr = t >> 2, sc = (t & 3) * 8;
    int lane = t & 63, w = t >> 6;
    int mo = (w & 1) * 32, no = (w >> 1) * 32;
    int quad = lane >> 4, r = lane & 15;

    // issue all x loads + first B chunk up front (latency hidden under LN math)
    float xv[64];
    const float* xp = &X[(size_t)(m0 + sr) * 256 + sc];
#pragma unroll
    for (int c = 0; c < 8; ++c) {
        *(float4*)&xv[c * 8] = *(const float4*)(xp + c * 32);
        *(float4*)&xv[c * 8 + 4] = *(const float4*)(xp + c * 32 + 4);
    }
    const short* Bp = &Bt[(size_t)(n0 + sr) * 256 + sc];
    int4 bv = *(const int4*)Bp;
    gs[t] = lg[t];
    bs_[t] = lb[t];

    float s1 = 0.f, s2 = 0.f;
#pragma unroll
    for (int j = 0; j < 64; ++j) {
        s1 += xv[j];
        s2 += xv[j] * xv[j];
    }
    s1 += __shfl_xor(s1, 1, 64); s1 += __shfl_xor(s1, 2, 64);
    s2 += __shfl_xor(s2, 1, 64); s2 += __shfl_xor(s2, 2, 64);
    float mean = s1 * (1.0f / 256.0f);
    float inv = rsqrtf(s2 * (1.0f / 256.0f) - mean * mean + EPS_);
    __syncthreads();  // gs/bs_ visible

    int4 a_regs[8];
#pragma unroll
    for (int c = 0; c < 8; ++c) {
        float tmp[8];
#pragma unroll
        for (int j = 0; j < 8; ++j)
            tmp[j] = (xv[c * 8 + j] - mean) * inv * gs[c * 32 + sc + j] + bs_[c * 32 + sc + j];
        a_regs[c] = pack8(tmp);
    }

    // stage chunk 0, prefetch chunk 1
    *(int4*)&As[0][sr][sc] = a_regs[0];
    *(int4*)&Bs[0][sr][sc] = bv;
    bv = *(const int4*)(Bp + 32);
    __syncthreads();

    f32x4 acc00 = {}, acc01 = {}, acc10 = {}, acc11 = {};
#pragma unroll
    for (int c = 0; c < 8; ++c) {
        int p = c & 1;
        if (c + 1 < 8) {
            *(int4*)&As[p ^ 1][sr][sc] = a_regs[c + 1];
            *(int4*)&Bs[p ^ 1][sr][sc] = bv;
            if (c + 2 < 8) bv = *(const int4*)(Bp + (c + 2) * 32);
        }
        bf16x8 a0 = *(const bf16x8*)&As[p][mo + r][quad * 8];
        bf16x8 a1 = *(const bf16x8*)&As[p][mo + 16 + r][quad * 8];
        bf16x8 b0 = *(const bf16x8*)&Bs[p][no + r][quad * 8];
        bf16x8 b1 = *(const bf16x8*)&Bs[p][no + 16 + r][quad * 8];
        acc00 = __builtin_amdgcn_mfma_f32_16x16x32_bf16(a0, b0, acc00, 0, 0, 0);
        acc01 = __builtin_amdgcn_mfma_f32_16x16x32_bf16(a0, b1, acc01, 0, 0, 0);
        acc10 = __builtin_amdgcn_mfma_f32_16x16x32_bf16(a1, b0, acc10, 0, 0, 0);
        acc11 = __builtin_amdgcn_mfma_f32_16x16x32_bf16(a1, b1, acc11, 0, 0, 0);
        if (c + 1 < 8) __syncthreads();
    }
    gemm_epilogue<EPI, HAS_BIAS>(acc00, acc01, acc10, acc11, bias, Cf, Cb, Nout, 0,
                                 m0, n0, mo, no, quad, r);
}

// fused LN1 + Q/K/V projection: q,k -> bf16; v -> f16 (PV mfma uses f16)
__global__ __launch_bounds__(256) void gemm_ln_qkv(const float* __restrict__ X,
                                                   const float* __restrict__ lg, const float* __restrict__ lb,
                                                   const short* __restrict__ wq, const short* __restrict__ wk,
                                                   const short* __restrict__ wv,
                                                   short* __restrict__ q, short* __restrict__ k,
                                                   short* __restrict__ v) {
    if (blockIdx.z == 0)
        gemm_ln_body<4, false>(X, lg, lb, wq, nullptr, nullptr, q, D_);
    else if (blockIdx.z == 1)
        gemm_ln_body<4, false>(X, lg, lb, wk, nullptr, nullptr, k, D_);
    else
        gemm_ln_body<5, false>(X, lg, lb, wv, nullptr, nullptr, v, D_);
}

// fused LN2 + FFN1 (bias+relu -> bf16)
__global__ __launch_bounds__(256) void gemm_ln_relu(const float* __restrict__ X,
                                                    const float* __restrict__ lg, const float* __restrict__ lb,
                                                    const short* __restrict__ Bt, const float* __restrict__ bias,
                                                    short* __restrict__ C) {
    gemm_ln_body<1, true>(X, lg, lb, Bt, bias, nullptr, C, FF_);
}

// fused final LN + generator (bias -> fp32)
__global__ __launch_bounds__(256) void gemm_ln_bias(const float* __restrict__ X,
                                                    const float* __restrict__ lg, const float* __restrict__ lb,
                                                    const short* __restrict__ Bt, const float* __restrict__ bias,
                                                    float* __restrict__ C) {
    gemm_ln_body<3, true>(X, lg, lb, Bt, bias, C, nullptr, V_);
}

template <int SPLITK, bool HAS_BIAS>
__global__ __launch_bounds__(256) void gemm_accum(const short* __restrict__ A, const short* __restrict__ Bt,
                                                  const float* __restrict__ bias, float* __restrict__ C,
                                                  int M, int K, int Nout) {
    int Kp = K / SPLITK;
    int kz = blockIdx.z;
    gemm_body<2, HAS_BIAS>(A, Bt, bias, C, nullptr, M, K, Nout, kz * Kp, kz * Kp + Kp, kz);
}

// MFMA flash attention. One wave (64 thr) per (b,h,q-tile of 16 queries).
__global__ __launch_bounds__(64) void attn_kernel(const short* __restrict__ q,
                                                  const short* __restrict__ k,
                                                  const _Float16* __restrict__ v,
                                                  short* __restrict__ z) {
    int blk = blockIdx.x;
    int bh = blk & 63;
    int qt = 15 - (blk >> 6);  // heavy q-tiles dispatched first
    int b = bh >> 3, h = bh & 7;
    int lane = threadIdx.x;
    int r = lane & 15, quad = lane >> 4;
    int row0 = b * L_;

    bf16x8 qf = *(const bf16x8*)&q[(size_t)(row0 + qt * 16 + r) * D_ + h * DK_ + quad * 8];
    f32x4 O0 = {}, O1 = {};
    float mA = -1e30f, den = 0.f;
    int nk = qt + 1;

    bf16x8 kf = *(const bf16x8*)&k[(size_t)(row0 + r) * D_ + h * DK_ + quad * 8];
    f16x4 va, vb;
    {
        const _Float16* vp = v + (size_t)(row0 + quad * 4) * D_ + h * DK_;
#pragma unroll
        for (int i = 0; i < 4; ++i) {
            va[i] = vp[(size_t)i * D_ + r];
            vb[i] = vp[(size_t)i * D_ + 16 + r];
        }
    }
    for (int kt = 0; kt < nk; ++kt) {
        bf16x8 kf_n = kf;
        f16x4 va_n = va, vb_n = vb;
        if (kt + 1 < nk) {
            kf_n = *(const bf16x8*)&k[(size_t)(row0 + (kt + 1) * 16 + r) * D_ + h * DK_ + quad * 8];
            const _Float16* vp = v + (size_t)(row0 + (kt + 1) * 16 + quad * 4) * D_ + h * DK_;
#pragma unroll
            for (int i = 0; i < 4; ++i) {
                va_n[i] = vp[(size_t)i * D_ + r];
                vb_n[i] = vp[(size_t)i * D_ + 16 + r];
            }
        }
        f32x4 zero = {};
        f32x4 s = __builtin_amdgcn_mfma_f32_16x16x32_bf16(kf, qf, zero, 0, 0, 0);
#pragma unroll
        for (int i2 = 0; i2 < 4; ++i2) s[i2] *= 0.17677669529663687f;
        if (kt == qt) {
#pragma unroll
            for (int i2 = 0; i2 < 4; ++i2)
                if (quad * 4 + i2 > r) s[i2] = -1e30f;
        }
        float tmax = fmaxf(fmaxf(s[0], s[1]), fmaxf(s[2], s[3]));
        tmax = fmaxf(tmax, __shfl_xor(tmax, 16, 64));
        tmax = fmaxf(tmax, __shfl_xor(tmax, 32, 64));
        float mn = fmaxf(mA, tmax);
        float alpha = __expf(mA - mn);
        mA = mn;
        float p0 = __expf(s[0] - mn), p1 = __expf(s[1] - mn);
        float p2 = __expf(s[2] - mn), p3 = __expf(s[3] - mn);
        float ts = (p0 + p1) + (p2 + p3);
        ts += __shfl_xor(ts, 16, 64);
        ts += __shfl_xor(ts, 32, 64);
        den = den * alpha + ts;
        f16x4 pf;
        pf[0] = (_Float16)p0; pf[1] = (_Float16)p1; pf[2] = (_Float16)p2; pf[3] = (_Float16)p3;
        float al[4];
#pragma unroll
        for (int i2 = 0; i2 < 4; ++i2) al[i2] = __shfl(alpha, quad * 4 + i2, 64);
#pragma unroll
        for (int i2 = 0; i2 < 4; ++i2) { O0[i2] *= al[i2]; O1[i2] *= al[i2]; }
        O0 = __builtin_amdgcn_mfma_f32_16x16x16f16(pf, va, O0, 0, 0, 0);
        O1 = __builtin_amdgcn_mfma_f32_16x16x16f16(pf, vb, O1, 0, 0, 0);
        kf = kf_n; va = va_n; vb = vb_n;
    }
#pragma unroll
    for (int i2 = 0; i2 < 4; ++i2) {
        float inv = 1.0f / __shfl(den, quad * 4 + i2, 64);
        int rowz = row0 + qt * 16 + quad * 4 + i2;
        z[(size_t)rowz * D_ + h * DK_ + r] = f2b(O0[i2] * inv);
        z[(size_t)rowz * D_ + h * DK_ + 16 + r] = f2b(O1[i2] * inv);
    }
}

// in-place log_softmax over V=2048, one block per row
__global__ void lsm_kernel(float* __restrict__ logits) {
    __shared__ float rm[4], rs[4];
    int row = blockIdx.x, t = threadIdx.x;
    float* p = logits + (size_t)row * V_;
    float vals[8];
    float mx = -INFINITY;
#pragma unroll
    for (int i = 0; i < 8; ++i) {
        vals[i] = p[t + i * 256];
        mx = fmaxf(mx, vals[i]);
    }
#pragma unroll
    for (int off = 32; off; off >>= 1) mx = fmaxf(mx, __shfl_xor(mx, off, 64));
    int w = t >> 6;
    if ((t & 63) == 0) rm[w] = mx;
    __syncthreads();
    mx = fmaxf(fmaxf(rm[0], rm[1]), fmaxf(rm[2], rm[3]));
    float s = 0.f;
#pragma unroll
    for (int i = 0; i < 8; ++i) s += __expf(vals[i] - mx);
#pragma unroll
    for (int off = 32; off; off >>= 1) s += __shfl_xor(s, off, 64);
    if ((t & 63) == 0) rs[w] = s;
    __syncthreads();
    s = rs[0] + rs[1] + rs[2] + rs[3];
    float lse = mx + logf(s);
#pragma unroll
    for (int i = 0; i < 8; ++i) p[t + i * 256] = vals[i] - lse;
}

extern "C" void kernel_launch(void* const* d_in, const int* in_sizes, int n_in,
                              void* d_out, int out_size, void* d_ws, size_t ws_size,
                              hipStream_t stream) {
    const int* tokens = (const int*)d_in[0];
    const int* positions = (const int*)d_in[1];
    // d_in[2]=src, d_in[3]=dst: deterministic causal structure — unused
    const float* vtab = (const float*)d_in[4];
    const float* ctab = (const float*)d_in[5];
    const float* ptab = (const float*)d_in[6];
    const float* ln1_g = (const float*)d_in[7];
    const float* ln1_b = (const float*)d_in[8];
    const float* Wq = (const float*)d_in[9];
    const float* Wk = (const float*)d_in[10];
    const float* Wv = (const float*)d_in[11];
    const float* Wo = (const float*)d_in[12];
    const float* ln2_g = (const float*)d_in[13];
    const float* ln2_b = (const float*)d_in[14];
    const float* W1 = (const float*)d_in[15];
    const float* b1 = (const float*)d_in[16];
    const float* W2 = (const float*)d_in[17];
    const float* b2 = (const float*)d_in[18];
    const float* lnf_g = (const float*)d_in[19];
    const float* lnf_b = (const float*)d_in[20];
    const float* Wgen = (const float*)d_in[21];
    const float* bgen = (const float*)d_in[22];

    char* p = (char*)d_ws;
    float* x = (float*)p;      p += (size_t)N_ * D_ * 4;
    short* qb = (short*)p;     p += (size_t)N_ * D_ * 4;   // bf16 (padded alloc)
    short* kb = (short*)p;     p += (size_t)N_ * D_ * 4;   // bf16
    short* vbh = (short*)p;    p += (size_t)N_ * D_ * 4;   // f16
    short* zbb = (short*)p;    p += (size_t)N_ * D_ * 2;
    short* hbb = (short*)p;    p += (size_t)N_ * FF_ * 2;
    short* wqT = (short*)p;    p += (size_t)NL_ * D_ * D_ * 2;
    short* wkT = (short*)p;    p += (size_t)NL_ * D_ * D_ * 2;
    short* wvT = (short*)p;    p += (size_t)NL_ * D_ * D_ * 2;
    short* woT = (short*)p;    p += (size_t)NL_ * D_ * D_ * 2;
    short* w1T = (short*)p;    p += (size_t)NL_ * D_ * FF_ * 2;
    short* w2T = (short*)p;    p += (size_t)NL_ * FF_ * D_ * 2;
    short* wgT = (short*)p;    p += (size_t)D_ * V_ * 2;
    float* out = (float*)d_out;

    dim3 tb(32, 8);
    transpose_all<<<5632, tb, 0, stream>>>(Wq, Wk, Wv, Wo, W1, W2, Wgen,
                                           wqT, wkT, wvT, woT, w1T, w2T, wgT,
                                           tokens, positions, vtab, ctab, ptab, x);

    dim3 gQKV(N_ / 64, D_ / 64, 3);
    dim3 gWo(N_ / 64, D_ / 64, 2);
    dim3 gW1(N_ / 64, FF_ / 64);
    dim3 gW2(N_ / 64, D_ / 64, 4);
    dim3 gGen(N_ / 64, V_ / 64);
    for (int i = 0; i < NL_; ++i) {
        gemm_ln_qkv<<<gQKV, 256, 0, stream>>>(x, ln1_g + i * D_, ln1_b + i * D_,
                                              wqT + (size_t)i * D_ * D_, wkT + (size_t)i * D_ * D_,
                                              wvT + (size_t)i * D_ * D_, qb, kb, vbh);
        attn_kernel<<<B_ * H_ * 16, 64, 0, stream>>>(qb, kb, (const _Float16*)vbh, zbb);
        gemm_accum<2, false><<<gWo, 256, 0, stream>>>(zbb, woT + (size_t)i * D_ * D_, nullptr, x, N_, D_, D_);
        gemm_ln_relu<<<gW1, 256, 0, stream>>>(x, ln2_g + i * D_, ln2_b + i * D_,
                                              w1T + (size_t)i * D_ * FF_, b1 + (size_t)i * FF_, hbb);
        gemm_accum<4, true><<<gW2, 256, 0, stream>>>(hbb, w2T + (size_t)i * FF_ * D_, b2 + (size_t)i * D_,
                                                     x, N_, FF_, D_);
    }
    gemm_ln_bias<<<gGen, 256, 0, stream>>>(x, lnf_g, lnf_b, wgT, bgen, out);
    lsm_kernel<<<N_, 256, 0, stream>>>(out);
}